// Round 3
// baseline (125.590 us; speedup 1.0000x reference)
//
#include <hip/hip_runtime.h>
#include <math.h>

#define KBINS 16
#define HID 16
// ln(0.02)
#define LN_SIGMA1 (-3.912023005428146f)

// Native 16B vector type: __builtin_nontemporal_store requires a native
// vector, not HIP's float4 class.
typedef float floatx4 __attribute__((ext_vector_type(4)));

// Force a wave-uniform value into an SGPR (weights are uniform per block).
__device__ __forceinline__ float to_sgpr(float x) {
    return __int_as_float(__builtin_amdgcn_readfirstlane(__float_as_int(x)));
}

// Per-element epilogue: mu_x/sigma_x -> 16 bin probabilities (4x floatx4).
// Rolling cdf difference: bit-identical to cdf[j+1]-cdf[j] with cdf[0]=0, cdf[16]=1.
// erf via A&S 7.1.27, |err|<=5e-4; saturates through rcp(inf)=0.
__device__ __forceinline__ void bins16(
    float m, float o0, float o1,
    float inv_gamma, float var_scale, bool tiny_t,
    floatx4 r[4])
{
    float mu_x = fmaf(m, inv_gamma, -var_scale * o0);
    float lse  = fminf(fmaxf(o1, -10.0f), 10.0f);
    float sigma_x = fmaxf(var_scale * __expf(lse), 0.02f);
    if (tiny_t) { mu_x = 0.0f; sigma_x = 1.0f; }   // wave-uniform branch

    const float inv = 0.70710678118f * __builtin_amdgcn_rcpf(sigma_x);
    const float x0  = (-0.875f - mu_x) * inv;   // boundary j=1
    const float stp = 0.125f * inv;

    float prev = 0.0f;
#pragma unroll
    for (int s = 0; s < 4; ++s) {
        float v[4];
#pragma unroll
        for (int q = 0; q < 4; ++q) {
            const int j = 4 * s + q + 1;
            float cur;
            if (j == KBINS) {
                cur = 1.0f;
            } else {
                float x  = fmaf((float)(j - 1), stp, x0);
                float ax = fabsf(x);
                float p  = fmaf(0.078108f, ax, 0.000972f);
                p        = fmaf(p, ax, 0.230389f);
                p        = fmaf(p, ax, 0.278393f);
                float qq = fmaf(p, ax, 1.0f);
                float q2 = qq * qq;
                float q4 = q2 * q2;
                float hr = 0.5f * __builtin_amdgcn_rcpf(q4);
                cur = (x >= 0.0f) ? (1.0f - hr) : hr;
            }
            v[q] = cur - prev;
            prev = cur;
        }
        floatx4 rr = { v[0], v[1], v[2], v[3] };
        r[s] = rr;
    }
}

__global__ __launch_bounds__(256, 4) void bfn_kernel(
    const float* __restrict__ mu,
    const float* __restrict__ t,
    const float* __restrict__ W1,   // [2,16]
    const float* __restrict__ b1,   // [16]
    const float* __restrict__ W2,   // [16,2]
    const float* __restrict__ b2,   // [2]
    float* __restrict__ out,        // [B,D,16]
    int D)
{
    // 512 rows x 20 words (80 B row stride: 16B-aligned, conflict-free for
    // both the b128 writes and the strided b128 transpose reads). 40 KB ->
    // exactly 4 blocks/CU against the 160 KB LDS pool.
    __shared__ float lds[512 * 20];

    const int b   = blockIdx.y;
    const int tid = threadIdx.x;
    const int d0  = blockIdx.x * 512;

    // Two elements per thread, 256 apart (keeps both mu loads and the LDS
    // staging geometry identical to the proven 1-elem version).
    const int dA = d0 + tid;
    const int dB = d0 + 256 + tid;
    const bool vA = (dA < D);
    const bool vB = (dB < D);

    // Issue mu loads first so their latency overlaps the weight prologue.
    const float mA = vA ? mu[(size_t)b * D + dA] : 0.0f;
    const float mB = vB ? mu[(size_t)b * D + dB] : 0.0f;

    // ---- wave-uniform per-row constants ----
    const float tb    = t[b];
    const float gamma = -expm1f(2.0f * tb * LN_SIGMA1);  // 1 - 0.02^(2t), no cancellation
    const float e2t   = 1.0f - gamma;                    // 0.02^(2t)
    const float inv_gamma = 1.0f / gamma;
    const float var_scale = sqrtf(e2t * inv_gamma);
    const bool  tiny_t = (tb < 1e-6f);

    // weights -> SGPRs (uniform); c1 = t*W1[1]+b1 stays VGPR (1 SGPR/VALU rule)
    float w1a[HID], c1[HID], w20[HID], w21[HID];
#pragma unroll
    for (int i = 0; i < HID; ++i) {
        w1a[i] = to_sgpr(W1[i]);
        c1[i]  = fmaf(tb, W1[HID + i], b1[i]);
        w20[i] = to_sgpr(W2[2 * i]);
        w21[i] = to_sgpr(W2[2 * i + 1]);
    }
    const float bias0 = to_sgpr(b2[0]);
    const float bias1 = to_sgpr(b2[1]);

    // ---- MLP for both elements, interleaved (2 independent chains/lane) ----
    // gelu(tanh approx) == pre * sigmoid(2u), u = 0.79788456*(pre + 0.044715 pre^3)
    float oA0 = bias0, oA1 = bias1;
    float oB0 = bias0, oB1 = bias1;
#pragma unroll
    for (int i = 0; i < HID; ++i) {
        float preA = fmaf(mA, w1a[i], c1[i]);
        float preB = fmaf(mB, w1a[i], c1[i]);
        float pA2  = preA * preA;
        float pB2  = preB * preB;
        float zA   = preA * fmaf(pA2, -0.0713552235f, -1.5957691216f);  // -2u
        float zB   = preB * fmaf(pB2, -0.0713552235f, -1.5957691216f);
        float eA   = __expf(zA);
        float eB   = __expf(zB);
        float hA   = preA * __builtin_amdgcn_rcpf(1.0f + eA);
        float hB   = preB * __builtin_amdgcn_rcpf(1.0f + eB);
        oA0 = fmaf(hA, w20[i], oA0);
        oA1 = fmaf(hA, w21[i], oA1);
        oB0 = fmaf(hB, w20[i], oB0);
        oB1 = fmaf(hB, w21[i], oB1);
    }

    const bool full = (d0 + 512 <= D);   // D=49152 -> always true; tail for safety
    if (full) {
        // Stage element A, then B (keeps peak live VGPRs at one r[4] set).
        {
            floatx4 r[4];
            bins16(mA, oA0, oA1, inv_gamma, var_scale, tiny_t, r);
            floatx4* rowA = (floatx4*)(lds + tid * 20);
#pragma unroll
            for (int s = 0; s < 4; ++s) rowA[s] = r[s];
        }
        {
            floatx4 r[4];
            bins16(mB, oB0, oB1, inv_gamma, var_scale, tiny_t, r);
            floatx4* rowB = (floatx4*)(lds + (tid + 256) * 20);
#pragma unroll
            for (int s = 0; s < 4; ++s) rowB[s] = r[s];
        }
        __syncthreads();
        // Block's 32 KB written fully coalesced; out is never re-read -> nt.
        floatx4* og = (floatx4*)out + ((size_t)b * D + d0) * 4;
#pragma unroll
        for (int s = 0; s < 8; ++s) {
            int f = s * 256 + tid;          // block-local float4 index, coalesced
            int e = f >> 2;                 // source element row
            int c = (f & 3) << 2;           // word offset in row
            __builtin_nontemporal_store(*(const floatx4*)(lds + e * 20 + c), og + f);
        }
    } else {
        if (vA) {
            floatx4 r[4];
            bins16(mA, oA0, oA1, inv_gamma, var_scale, tiny_t, r);
            floatx4* op = (floatx4*)(out + ((size_t)b * D + dA) * (size_t)KBINS);
#pragma unroll
            for (int s = 0; s < 4; ++s) op[s] = r[s];
        }
        if (vB) {
            floatx4 r[4];
            bins16(mB, oB0, oB1, inv_gamma, var_scale, tiny_t, r);
            floatx4* op = (floatx4*)(out + ((size_t)b * D + dB) * (size_t)KBINS);
#pragma unroll
            for (int s = 0; s < 4; ++s) op[s] = r[s];
        }
    }
}

extern "C" void kernel_launch(void* const* d_in, const int* in_sizes, int n_in,
                              void* d_out, int out_size, void* d_ws, size_t ws_size,
                              hipStream_t stream) {
    const float* mu = (const float*)d_in[0];
    const float* t  = (const float*)d_in[1];
    const float* W1 = (const float*)d_in[2];
    const float* b1 = (const float*)d_in[3];
    const float* W2 = (const float*)d_in[4];
    const float* b2 = (const float*)d_in[5];
    float* out = (float*)d_out;

    const int B = in_sizes[1];          // t is [B,1]
    const int D = in_sizes[0] / B;      // mu is [B,D]

    dim3 block(256);
    dim3 grid((D + 511) / 512, B);
    bfn_kernel<<<grid, block, 0, stream>>>(mu, t, W1, b1, W2, b2, out, D);
}

// Round 4
// 123.827 us; speedup vs baseline: 1.0142x; 1.0142x over previous
//
#include <hip/hip_runtime.h>
#include <math.h>

#define KBINS 16
#define HID 16
// ln(0.02)
#define LN_SIGMA1 (-3.912023005428146f)
#define LOG2E 1.4426950408889634f

// Native 16B vector type (works with both LDS and global 128-bit ops).
typedef float floatx4 __attribute__((ext_vector_type(4)));

// Force a wave-uniform value into an SGPR (weights are uniform per block).
__device__ __forceinline__ float to_sgpr(float x) {
    return __int_as_float(__builtin_amdgcn_readfirstlane(__float_as_int(x)));
}

// Occupancy is the experiment: 20 KB LDS (8 blocks/CU = 160 KB exactly) and
// <=64 VGPR (launch_bounds 256,8) -> 8 waves/SIMD, double the prior 4.
__global__ __launch_bounds__(256, 8) void bfn_kernel(
    const float* __restrict__ mu,
    const float* __restrict__ t,
    const float* __restrict__ W1,   // [2,16]
    const float* __restrict__ b1,   // [16]
    const float* __restrict__ W2,   // [16,2]
    const float* __restrict__ b2,   // [2]
    float* __restrict__ out,        // [B,D,16]
    int D)
{
    // 256 rows x 20 words (80 B row stride: 16B-aligned, conflict-free for
    // both the b128 writes and the strided b128 transpose reads).
    __shared__ float lds[256 * 20];

    const int b   = blockIdx.y;
    const int tid = threadIdx.x;
    const int d0  = blockIdx.x * 256;
    const int d   = d0 + tid;
    const bool valid = (d < D);

    // mu load issued first; latency overlaps the uniform prologue.
    const float m = valid ? mu[(size_t)b * D + d] : 0.0f;

    // ---- wave-uniform per-row constants ----
    const float tb    = t[b];
    const float gamma = -expm1f(2.0f * tb * LN_SIGMA1);  // 1 - 0.02^(2t)
    const float e2t   = 1.0f - gamma;                    // 0.02^(2t)
    const float inv_gamma = to_sgpr(1.0f / gamma);
    const float var_scale = to_sgpr(sqrtf(e2t * inv_gamma));
    const bool  tiny_t = (tb < 1e-6f);

    // ALL weights to SGPRs, including c1 (it is uniform: tb*W1[1]+b1).
    // The 1-SGPR-per-VALU rule costs one v_mov per hidden unit in the MLP
    // loop, but frees 16 VGPRs -> the 64-VGPR occupancy step.
    float w1a[HID], c1[HID], w20[HID], w21[HID];
#pragma unroll
    for (int i = 0; i < HID; ++i) {
        w1a[i] = to_sgpr(W1[i]);
        c1[i]  = to_sgpr(fmaf(tb, W1[HID + i], b1[i]));
        w20[i] = to_sgpr(W2[2 * i]);
        w21[i] = to_sgpr(W2[2 * i + 1]);
    }
    const float bias0 = to_sgpr(b2[0]);
    const float bias1 = to_sgpr(b2[1]);

    // ---- MLP: gelu(tanh approx) == pre * sigmoid(2u)
    // exp(-2u) computed as exp2 with the log2e baked into the coefficients:
    // z2 = pre * (p2 * (-0.0713552235*log2e) + (-1.5957691216*log2e))
    float o0 = bias0, o1 = bias1;
#pragma unroll
    for (int i = 0; i < HID; ++i) {
        float pre = fmaf(m, w1a[i], c1[i]);
        float p2  = pre * pre;
        float z2  = pre * fmaf(p2, -0.1029440437f, -2.3022081926f);  // -2u*log2e
        float e   = __builtin_amdgcn_exp2f(z2);
        float h   = pre * __builtin_amdgcn_rcpf(1.0f + e);
        o0 = fmaf(h, w20[i], o0);
        o1 = fmaf(h, w21[i], o1);
    }

    float mu_x = fmaf(m, inv_gamma, -var_scale * o0);
    float lse  = fminf(fmaxf(o1, -10.0f), 10.0f);
    float sigma_x = fmaxf(var_scale * __builtin_amdgcn_exp2f(lse * LOG2E), 0.02f);
    if (tiny_t) { mu_x = 0.0f; sigma_x = 1.0f; }   // wave-uniform branch

    const float inv = 0.70710678118f * __builtin_amdgcn_rcpf(sigma_x);
    const float x0  = (-0.875f - mu_x) * inv;   // boundary j=1
    const float stp = 0.125f * inv;

    // cdf at boundaries 1..15 (0 and 16 exact 0/1), rolling difference,
    // each group of 4 written to LDS immediately (live set stays tiny).
    // erf via A&S 7.1.27: erf(|x|) ~= 1 - q^-4, |err|<=5e-4; saturates
    // through rcp(inf)=0.
    floatx4* row = (floatx4*)(lds + tid * 20);
    float prev = 0.0f;
#pragma unroll
    for (int s = 0; s < 4; ++s) {
        float v[4];
#pragma unroll
        for (int q = 0; q < 4; ++q) {
            const int j = 4 * s + q + 1;
            float cur;
            if (j == KBINS) {
                cur = 1.0f;
            } else {
                float x  = fmaf((float)(j - 1), stp, x0);
                float ax = fabsf(x);
                float p  = fmaf(0.078108f, ax, 0.000972f);
                p        = fmaf(p, ax, 0.230389f);
                p        = fmaf(p, ax, 0.278393f);
                float qq = fmaf(p, ax, 1.0f);
                float q2 = qq * qq;
                float q4 = q2 * q2;
                float hr = 0.5f * __builtin_amdgcn_rcpf(q4);
                cur = (x >= 0.0f) ? (1.0f - hr) : hr;
            }
            v[q] = cur - prev;
            prev = cur;
        }
        floatx4 rr = { v[0], v[1], v[2], v[3] };
        row[s] = rr;
    }

    const bool full = (d0 + 256 <= D);   // D=49152 -> always true; tail for safety
    if (full) {
        __syncthreads();
        // Block's 16 KB written fully coalesced (plain stores: NT measured
        // slightly negative in R3).
        floatx4* og = (floatx4*)out + ((size_t)b * D + d0) * 4;
#pragma unroll
        for (int s = 0; s < 4; ++s) {
            int f = s * 256 + tid;          // block-local float4 index, coalesced
            int e = f >> 2;                 // source element row
            int c = (f & 3) << 2;           // word offset in row
            og[f] = *(const floatx4*)(lds + e * 20 + c);
        }
    } else if (valid) {
        floatx4* op = (floatx4*)(out + ((size_t)b * D + d) * (size_t)KBINS);
#pragma unroll
        for (int s = 0; s < 4; ++s) op[s] = row[s];
    }
}

extern "C" void kernel_launch(void* const* d_in, const int* in_sizes, int n_in,
                              void* d_out, int out_size, void* d_ws, size_t ws_size,
                              hipStream_t stream) {
    const float* mu = (const float*)d_in[0];
    const float* t  = (const float*)d_in[1];
    const float* W1 = (const float*)d_in[2];
    const float* b1 = (const float*)d_in[3];
    const float* W2 = (const float*)d_in[4];
    const float* b2 = (const float*)d_in[5];
    float* out = (float*)d_out;

    const int B = in_sizes[1];          // t is [B,1]
    const int D = in_sizes[0] / B;      // mu is [B,D]

    dim3 block(256);
    dim3 grid((D + 255) / 256, B);
    bfn_kernel<<<grid, block, 0, stream>>>(mu, t, W1, b1, W2, b2, out, D);
}